// Round 1
// 326.188 us; speedup vs baseline: 1.0026x; 1.0026x over previous
//
#include <hip/hip_runtime.h>

#define NBINS 4
#define BLOCK 256
#define WAVES_PER_BLOCK (BLOCK / 64)
#define NBLOCKS 2048

struct WS {
    float sum_v[NBINS];  // per-bin sum of 0.5*d2 + 0.1*ad2
    float cnt[NBINS];    // per-bin count (exact in float up to 2^24)
};

// Per-point update, branchless. One raw v_sqrt per point:
// (|x|-|y|)^2 = sx + sy - 2*sqrt(sx*sy). Exclusive binning (ref double-counts
// exact boundary points; ~1 point in 16.7M, error ~2e-7 << 0.166 threshold).
__device__ __forceinline__ void accum_point(float x0, float x1, float y0, float y1,
                                            float d,
                                            float (&acc)[NBINS], float (&cnt)[NBINS]) {
    float sx = fmaf(x1, x1, x0 * x0);
    float sy = fmaf(y1, y1, y0 * y0);
    float dx0 = x0 - y0, dx1 = x1 - y1;
    float d2 = fmaf(dx1, dx1, dx0 * dx0);
    float t = __builtin_amdgcn_sqrtf(sx * sy);  // raw v_sqrt_f32, ~1 ulp
    float ad2 = sx + sy - 2.0f * t;             // (|x|-|y|)^2
    float v = fmaf(0.1f, ad2, 0.5f * d2);
    bool c1 = d < 0.25f;
    bool c2 = d < 0.5f;
    bool c3 = d < 0.75f;
    float m0 = c1 ? 1.0f : 0.0f;
    float m1 = (c2 && !c1) ? 1.0f : 0.0f;
    float m2 = (c3 && !c2) ? 1.0f : 0.0f;
    float m3 = c3 ? 0.0f : 1.0f;
    acc[0] = fmaf(v, m0, acc[0]);
    acc[1] = fmaf(v, m1, acc[1]);
    acc[2] = fmaf(v, m2, acc[2]);
    acc[3] = fmaf(v, m3, acc[3]);
    cnt[0] += m0;
    cnt[1] += m1;
    cnt[2] += m2;
    cnt[3] += m3;
}

__device__ __forceinline__ void accum2(const float4& xv, const float4& yv,
                                       const float2& dv,
                                       float (&acc)[NBINS], float (&cnt)[NBINS]) {
    accum_point(xv.x, xv.y, yv.x, yv.y, dv.x, acc, cnt);
    accum_point(xv.z, xv.w, yv.z, yv.w, dv.y, acc, cnt);
}

// Grid-INTERLEAVED streaming: all 524288 threads advance through one dense
// moving window (8 MB per stream per step) instead of 2048 private chunks.
// Rationale: per-block chunking creates ~6K concurrent sequential HBM streams
// -> DRAM row thrash; counters showed 2.7 TB/s delivered with VALU 13% and
// HBM 17%, i.e. neither roofline. Dense front = row-buffer locality.
__global__ __launch_bounds__(BLOCK, 4) void radial_loss_main(
    const float* __restrict__ x, const float* __restrict__ y,
    const float* __restrict__ dist, WS* __restrict__ ws, int n) {
    float acc[NBINS] = {0.f, 0.f, 0.f, 0.f};
    float cnt[NBINS] = {0.f, 0.f, 0.f, 0.f};

    const int n2 = n >> 1;  // float4(x,y) / float2(dist) index space: 2 points each
    const float4* __restrict__ x4 = (const float4*)x;
    const float4* __restrict__ y4 = (const float4*)y;
    const float2* __restrict__ dd = (const float2*)dist;

    const int stride = NBLOCKS * BLOCK;            // 524288; n2 = 16*stride at N=16.7M
    const int nfull = n2 / stride;                 // uniform full steps for ALL threads
    int i = blockIdx.x * BLOCK + threadIdx.x;

    // Depth-3 software pipeline: while computing stage A, stages B and C's
    // loads (6 instructions, 80 B/lane) are in flight.
    float4 xa, ya, xb, yb;
    float2 da, db;
    if (nfull >= 1) { xa = x4[i]; ya = y4[i]; da = dd[i]; }
    if (nfull >= 2) { xb = x4[i + stride]; yb = y4[i + stride]; db = dd[i + stride]; }
#pragma unroll 2
    for (int k = 0; k + 2 < nfull; ++k) {
        float4 xc = x4[i + 2 * stride];
        float4 yc = y4[i + 2 * stride];
        float2 dc = dd[i + 2 * stride];
        accum2(xa, ya, da, acc, cnt);
        xa = xb; ya = yb; da = db;
        xb = xc; yb = yc; db = dc;
        i += stride;
    }
    if (nfull >= 2) {
        accum2(xa, ya, da, acc, cnt);
        xa = xb; ya = yb; da = db;
        i += stride;
    }
    if (nfull >= 1) {
        accum2(xa, ya, da, acc, cnt);
        i += stride;
    }
    // remainder region [nfull*stride, n2): each thread owns at most one index
    if (i < n2) {
        accum2(x4[i], y4[i], dd[i], acc, cnt);
    }
    // odd-n tail (n even in practice)
    if (blockIdx.x == 0) {
        for (int p = (n2 << 1) + threadIdx.x; p < n; p += BLOCK) {
            accum_point(x[2 * p], x[2 * p + 1], y[2 * p], y[2 * p + 1], dist[p],
                        acc, cnt);
        }
    }

    // wave-64 shuffle reduction (8 values)
#pragma unroll
    for (int off = 32; off > 0; off >>= 1) {
#pragma unroll
        for (int b = 0; b < NBINS; ++b) {
            acc[b] += __shfl_down(acc[b], off);
            cnt[b] += __shfl_down(cnt[b], off);
        }
    }

    __shared__ float sm_v[WAVES_PER_BLOCK][NBINS];
    __shared__ float sm_c[WAVES_PER_BLOCK][NBINS];
    const int wave = threadIdx.x >> 6;
    const int lane = threadIdx.x & 63;
    if (lane == 0) {
#pragma unroll
        for (int b = 0; b < NBINS; ++b) {
            sm_v[wave][b] = acc[b];
            sm_c[wave][b] = cnt[b];
        }
    }
    __syncthreads();
    if (threadIdx.x < NBINS) {
        const int b = threadIdx.x;
        float tv = 0.f, tc = 0.f;
#pragma unroll
        for (int w = 0; w < WAVES_PER_BLOCK; ++w) {
            tv += sm_v[w][b];
            tc += sm_c[w][b];
        }
        atomicAdd(&ws->sum_v[b], tv);
        atomicAdd(&ws->cnt[b], tc);
    }
}

__global__ void radial_loss_final(const WS* __restrict__ ws, float* __restrict__ out) {
    if (threadIdx.x == 0 && blockIdx.x == 0) {
        float loss = 0.f;
#pragma unroll
        for (int b = 0; b < NBINS; ++b) {
            float c = ws->cnt[b];
            if (c > 0.f) loss += ws->sum_v[b] / c;
        }
        out[0] = loss;
    }
}

extern "C" void kernel_launch(void* const* d_in, const int* in_sizes, int n_in,
                              void* d_out, int out_size, void* d_ws, size_t ws_size,
                              hipStream_t stream) {
    const float* x = (const float*)d_in[0];
    const float* y = (const float*)d_in[1];
    const float* dist = (const float*)d_in[2];
    float* out = (float*)d_out;
    WS* ws = (WS*)d_ws;
    const int n = in_sizes[2];  // dist element count = N

    hipMemsetAsync(ws, 0, sizeof(WS), stream);
    radial_loss_main<<<NBLOCKS, BLOCK, 0, stream>>>(x, y, dist, ws, n);
    radial_loss_final<<<1, 64, 0, stream>>>(ws, out);
}

// Round 2
// 320.260 us; speedup vs baseline: 1.0211x; 1.0185x over previous
//
#include <hip/hip_runtime.h>

#define NBINS 4
#define BLOCK 256
#define WAVES_PER_BLOCK (BLOCK / 64)
#define NBLOCKS 2048

typedef float f32x4 __attribute__((ext_vector_type(4)));
typedef float f32x2 __attribute__((ext_vector_type(2)));

struct WS {
    float sum_v[NBINS];  // per-bin sum of 0.5*d2 + 0.1*ad2
    float cnt[NBINS];    // per-bin count (exact in float up to 2^24)
};

// Per-point update, branchless. One raw v_sqrt per point:
// (|x|-|y|)^2 = sx + sy - 2*sqrt(sx*sy). Exclusive binning (ref double-counts
// exact boundary points; ~1 point in 16.7M, error ~2e-7 << 0.166 threshold).
__device__ __forceinline__ void accum_point(float x0, float x1, float y0, float y1,
                                            float d,
                                            float (&acc)[NBINS], float (&cnt)[NBINS]) {
    float sx = fmaf(x1, x1, x0 * x0);
    float sy = fmaf(y1, y1, y0 * y0);
    float dx0 = x0 - y0, dx1 = x1 - y1;
    float d2 = fmaf(dx1, dx1, dx0 * dx0);
    float t = __builtin_amdgcn_sqrtf(sx * sy);  // raw v_sqrt_f32, ~1 ulp
    float ad2 = sx + sy - 2.0f * t;             // (|x|-|y|)^2
    float v = fmaf(0.1f, ad2, 0.5f * d2);
    bool c1 = d < 0.25f;
    bool c2 = d < 0.5f;
    bool c3 = d < 0.75f;
    float m0 = c1 ? 1.0f : 0.0f;
    float m1 = (c2 && !c1) ? 1.0f : 0.0f;
    float m2 = (c3 && !c2) ? 1.0f : 0.0f;
    float m3 = c3 ? 0.0f : 1.0f;
    acc[0] = fmaf(v, m0, acc[0]);
    acc[1] = fmaf(v, m1, acc[1]);
    acc[2] = fmaf(v, m2, acc[2]);
    acc[3] = fmaf(v, m3, acc[3]);
    cnt[0] += m0;
    cnt[1] += m1;
    cnt[2] += m2;
    cnt[3] += m3;
}

__device__ __forceinline__ void accum2v(const f32x4 xv, const f32x4 yv,
                                        const f32x2 dv,
                                        float (&acc)[NBINS], float (&cnt)[NBINS]) {
    accum_point(xv.x, xv.y, yv.x, yv.y, dv.x, acc, cnt);
    accum_point(xv.z, xv.w, yv.z, yv.w, dv.y, acc, cnt);
}

__device__ __forceinline__ void accum2(const float4& xv, const float4& yv,
                                       const float2& dv,
                                       float (&acc)[NBINS], float (&cnt)[NBINS]) {
    accum_point(xv.x, xv.y, yv.x, yv.y, dv.x, acc, cnt);
    accum_point(xv.z, xv.w, yv.z, yv.w, dv.y, acc, cnt);
}

// Inline-asm load: SGPR base + 32-bit VGPR byte offset (saves a VGPR pair per
// address). Ring of 4 named stages; counted vmcnt keeps 9 load instructions
// (3 stages, ~7.7 KB/wave) in flight through every compute phase — the
// compiler had collapsed the C++-level pipeline to VGPR_Count=36 (~depth 1).
#define GLOAD4(dst, base, off) \
    asm volatile("global_load_dwordx4 %0, %1, %2" : "=v"(dst) : "v"(off), "s"(base))
#define GLOAD2(dst, base, off) \
    asm volatile("global_load_dwordx2 %0, %1, %2" : "=v"(dst) : "v"(off), "s"(base))
// Counted wait + rule-#18 fence (sched_barrier stops hipcc hoisting dependent
// VALU above the wait; "memory" alone does not order register-only ops).
#define VWAIT(n)                                             \
    do {                                                     \
        asm volatile("s_waitcnt vmcnt(" #n ")" ::: "memory"); \
        __builtin_amdgcn_sched_barrier(0);                   \
    } while (0)

__global__ __launch_bounds__(BLOCK, 4) void radial_loss_main(
    const float* __restrict__ x, const float* __restrict__ y,
    const float* __restrict__ dist, WS* __restrict__ ws, int n) {
    float acc[NBINS] = {0.f, 0.f, 0.f, 0.f};
    float cnt[NBINS] = {0.f, 0.f, 0.f, 0.f};

    const int n2 = n >> 1;  // float4(x,y) / float2(dist) index space: 2 points each
    const int stride = NBLOCKS * BLOCK;  // 524288; n2 = 16*stride at N=16.7M
    const int nfull = n2 / stride;       // uniform full steps for ALL threads
    int i = blockIdx.x * BLOCK + threadIdx.x;

    if (nfull >= 8 && (nfull & 3) == 0) {
        // ---- asm-pipelined path (taken for the bench shape: nfull == 16) ----
        f32x4 x0, y0, x1, y1, x2, y2, x3, y3;
        f32x2 d0, d1, d2, d3;
#define ISSUE(j, idx)                                       \
    do {                                                    \
        unsigned o16 = (unsigned)(idx) * 16u;               \
        unsigned o8 = (unsigned)(idx) * 8u;                 \
        GLOAD4(x##j, x, o16);                               \
        GLOAD4(y##j, y, o16);                               \
        GLOAD2(d##j, dist, o8);                             \
    } while (0)
        ISSUE(0, i);
        ISSUE(1, i + stride);
        ISSUE(2, i + 2 * stride);
        ISSUE(3, i + 3 * stride);
        int k = 0;
        for (; k + 8 <= nfull; k += 4) {
            VWAIT(9); accum2v(x0, y0, d0, acc, cnt); ISSUE(0, i + 4 * stride);
            VWAIT(9); accum2v(x1, y1, d1, acc, cnt); ISSUE(1, i + 5 * stride);
            VWAIT(9); accum2v(x2, y2, d2, acc, cnt); ISSUE(2, i + 6 * stride);
            VWAIT(9); accum2v(x3, y3, d3, acc, cnt); ISSUE(3, i + 7 * stride);
            i += 4 * stride;
        }
        // drain: exactly 4 stages outstanding here (loop exits at k == nfull-4)
        VWAIT(9); accum2v(x0, y0, d0, acc, cnt);
        VWAIT(6); accum2v(x1, y1, d1, acc, cnt);
        VWAIT(3); accum2v(x2, y2, d2, acc, cnt);
        VWAIT(0); accum2v(x3, y3, d3, acc, cnt);
        i += 4 * stride;
#undef ISSUE
    } else {
        // ---- generic fallback (not taken at N=16.7M) ----
        const float4* __restrict__ x4 = (const float4*)x;
        const float4* __restrict__ y4 = (const float4*)y;
        const float2* __restrict__ dd = (const float2*)dist;
        float4 xa, ya, xb, yb;
        float2 da, db;
        if (nfull >= 1) { xa = x4[i]; ya = y4[i]; da = dd[i]; }
        if (nfull >= 2) { xb = x4[i + stride]; yb = y4[i + stride]; db = dd[i + stride]; }
        for (int k = 0; k + 2 < nfull; ++k) {
            float4 xc = x4[i + 2 * stride];
            float4 yc = y4[i + 2 * stride];
            float2 dc = dd[i + 2 * stride];
            accum2(xa, ya, da, acc, cnt);
            xa = xb; ya = yb; da = db;
            xb = xc; yb = yc; db = dc;
            i += stride;
        }
        if (nfull >= 2) {
            accum2(xa, ya, da, acc, cnt);
            xa = xb; ya = yb; da = db;
            i += stride;
        }
        if (nfull >= 1) {
            accum2(xa, ya, da, acc, cnt);
            i += stride;
        }
    }

    // remainder region [nfull*stride, n2): each thread owns at most one index
    if (i < n2) {
        const float4* __restrict__ x4 = (const float4*)x;
        const float4* __restrict__ y4 = (const float4*)y;
        const float2* __restrict__ dd = (const float2*)dist;
        accum2(x4[i], y4[i], dd[i], acc, cnt);
    }
    // odd-n tail (n even in practice)
    if (blockIdx.x == 0) {
        for (int p = (n2 << 1) + threadIdx.x; p < n; p += BLOCK) {
            accum_point(x[2 * p], x[2 * p + 1], y[2 * p], y[2 * p + 1], dist[p],
                        acc, cnt);
        }
    }

    // wave-64 shuffle reduction (8 values)
#pragma unroll
    for (int off = 32; off > 0; off >>= 1) {
#pragma unroll
        for (int b = 0; b < NBINS; ++b) {
            acc[b] += __shfl_down(acc[b], off);
            cnt[b] += __shfl_down(cnt[b], off);
        }
    }

    __shared__ float sm_v[WAVES_PER_BLOCK][NBINS];
    __shared__ float sm_c[WAVES_PER_BLOCK][NBINS];
    const int wave = threadIdx.x >> 6;
    const int lane = threadIdx.x & 63;
    if (lane == 0) {
#pragma unroll
        for (int b = 0; b < NBINS; ++b) {
            sm_v[wave][b] = acc[b];
            sm_c[wave][b] = cnt[b];
        }
    }
    __syncthreads();
    if (threadIdx.x < NBINS) {
        const int b = threadIdx.x;
        float tv = 0.f, tc = 0.f;
#pragma unroll
        for (int w = 0; w < WAVES_PER_BLOCK; ++w) {
            tv += sm_v[w][b];
            tc += sm_c[w][b];
        }
        atomicAdd(&ws->sum_v[b], tv);
        atomicAdd(&ws->cnt[b], tc);
    }
}

__global__ void radial_loss_final(const WS* __restrict__ ws, float* __restrict__ out) {
    if (threadIdx.x == 0 && blockIdx.x == 0) {
        float loss = 0.f;
#pragma unroll
        for (int b = 0; b < NBINS; ++b) {
            float c = ws->cnt[b];
            if (c > 0.f) loss += ws->sum_v[b] / c;
        }
        out[0] = loss;
    }
}

extern "C" void kernel_launch(void* const* d_in, const int* in_sizes, int n_in,
                              void* d_out, int out_size, void* d_ws, size_t ws_size,
                              hipStream_t stream) {
    const float* x = (const float*)d_in[0];
    const float* y = (const float*)d_in[1];
    const float* dist = (const float*)d_in[2];
    float* out = (float*)d_out;
    WS* ws = (WS*)d_ws;
    const int n = in_sizes[2];  // dist element count = N

    hipMemsetAsync(ws, 0, sizeof(WS), stream);
    radial_loss_main<<<NBLOCKS, BLOCK, 0, stream>>>(x, y, dist, ws, n);
    radial_loss_final<<<1, 64, 0, stream>>>(ws, out);
}

// Round 3
// 314.758 us; speedup vs baseline: 1.0390x; 1.0175x over previous
//
#include <hip/hip_runtime.h>

#define NBINS 4
#define BLOCK 256
#define WAVES_PER_BLOCK (BLOCK / 64)
#define NBLOCKS 2048

typedef float f32x4 __attribute__((ext_vector_type(4)));
typedef float f32x2 __attribute__((ext_vector_type(2)));

struct WS {
    float sum_v[NBINS];  // per-bin sum of 0.5*d2 + 0.1*ad2
    float cnt[NBINS];    // per-bin count (exact in float up to 2^24)
};

// Per-point update, branchless. One raw v_sqrt per point:
// (|x|-|y|)^2 = sx + sy - 2*sqrt(sx*sy). Exclusive binning (ref double-counts
// exact boundary points; ~1 point in 16.7M, error ~2e-7 << 0.166 threshold).
__device__ __forceinline__ void accum_point(float x0, float x1, float y0, float y1,
                                            float d,
                                            float (&acc)[NBINS], float (&cnt)[NBINS]) {
    float sx = fmaf(x1, x1, x0 * x0);
    float sy = fmaf(y1, y1, y0 * y0);
    float dx0 = x0 - y0, dx1 = x1 - y1;
    float d2 = fmaf(dx1, dx1, dx0 * dx0);
    float t = __builtin_amdgcn_sqrtf(sx * sy);  // raw v_sqrt_f32, ~1 ulp
    float ad2 = sx + sy - 2.0f * t;             // (|x|-|y|)^2
    float v = fmaf(0.1f, ad2, 0.5f * d2);
    bool c1 = d < 0.25f;
    bool c2 = d < 0.5f;
    bool c3 = d < 0.75f;
    float m0 = c1 ? 1.0f : 0.0f;
    float m1 = (c2 && !c1) ? 1.0f : 0.0f;
    float m2 = (c3 && !c2) ? 1.0f : 0.0f;
    float m3 = c3 ? 0.0f : 1.0f;
    acc[0] = fmaf(v, m0, acc[0]);
    acc[1] = fmaf(v, m1, acc[1]);
    acc[2] = fmaf(v, m2, acc[2]);
    acc[3] = fmaf(v, m3, acc[3]);
    cnt[0] += m0;
    cnt[1] += m1;
    cnt[2] += m2;
    cnt[3] += m3;
}

__device__ __forceinline__ void accum2v(const f32x4 xv, const f32x4 yv,
                                        const f32x2 dv,
                                        float (&acc)[NBINS], float (&cnt)[NBINS]) {
    accum_point(xv.x, xv.y, yv.x, yv.y, dv.x, acc, cnt);
    accum_point(xv.z, xv.w, yv.z, yv.w, dv.y, acc, cnt);
}

// Non-temporal (nt) stream loads: zero intra-dispatch reuse, and the 320 MB
// working set thrashes the 256 MB L3 at a pinned 50% hit rate. Theory: the
// 2.6 TB/s delivered cap = per-CU outstanding-line pool / L3-thrash latency;
// nt (no-allocate / evict-first) removes MALL allocation+eviction from the
// miss path. R1 (access order) and R2 (ISA-enforced depth-12 MLP) were both
// exactly neutral, exonerating request supply.
__device__ __forceinline__ f32x4 ntload4(const f32x4* p) {
    return __builtin_nontemporal_load(p);
}
__device__ __forceinline__ f32x2 ntload2(const f32x2* p) {
    return __builtin_nontemporal_load(p);
}

__global__ __launch_bounds__(BLOCK, 4) void radial_loss_main(
    const float* __restrict__ x, const float* __restrict__ y,
    const float* __restrict__ dist, WS* __restrict__ ws, int n) {
    float acc[NBINS] = {0.f, 0.f, 0.f, 0.f};
    float cnt[NBINS] = {0.f, 0.f, 0.f, 0.f};

    const int n2 = n >> 1;  // float4(x,y) / float2(dist) index space: 2 points each
    const f32x4* __restrict__ x4 = (const f32x4*)x;
    const f32x4* __restrict__ y4 = (const f32x4*)y;
    const f32x2* __restrict__ dd = (const f32x2*)dist;

    const int stride = NBLOCKS * BLOCK;            // 524288; n2 = 16*stride at N=16.7M
    const int nfull = n2 / stride;                 // uniform full steps for ALL threads
    int i = blockIdx.x * BLOCK + threadIdx.x;

    // Depth-3 software pipeline (source-level; R2 proved ISA-enforced depth-4
    // is perf-identical, so keep the simpler form).
    f32x4 xa, ya, xb, yb;
    f32x2 da, db;
    if (nfull >= 1) { xa = ntload4(x4 + i); ya = ntload4(y4 + i); da = ntload2(dd + i); }
    if (nfull >= 2) {
        xb = ntload4(x4 + i + stride);
        yb = ntload4(y4 + i + stride);
        db = ntload2(dd + i + stride);
    }
#pragma unroll 2
    for (int k = 0; k + 2 < nfull; ++k) {
        f32x4 xc = ntload4(x4 + i + 2 * stride);
        f32x4 yc = ntload4(y4 + i + 2 * stride);
        f32x2 dc = ntload2(dd + i + 2 * stride);
        accum2v(xa, ya, da, acc, cnt);
        xa = xb; ya = yb; da = db;
        xb = xc; yb = yc; db = dc;
        i += stride;
    }
    if (nfull >= 2) {
        accum2v(xa, ya, da, acc, cnt);
        xa = xb; ya = yb; da = db;
        i += stride;
    }
    if (nfull >= 1) {
        accum2v(xa, ya, da, acc, cnt);
        i += stride;
    }
    // remainder region [nfull*stride, n2): each thread owns at most one index
    if (i < n2) {
        accum2v(ntload4(x4 + i), ntload4(y4 + i), ntload2(dd + i), acc, cnt);
    }
    // odd-n tail (n even in practice)
    if (blockIdx.x == 0) {
        for (int p = (n2 << 1) + threadIdx.x; p < n; p += BLOCK) {
            accum_point(x[2 * p], x[2 * p + 1], y[2 * p], y[2 * p + 1], dist[p],
                        acc, cnt);
        }
    }

    // wave-64 shuffle reduction (8 values)
#pragma unroll
    for (int off = 32; off > 0; off >>= 1) {
#pragma unroll
        for (int b = 0; b < NBINS; ++b) {
            acc[b] += __shfl_down(acc[b], off);
            cnt[b] += __shfl_down(cnt[b], off);
        }
    }

    __shared__ float sm_v[WAVES_PER_BLOCK][NBINS];
    __shared__ float sm_c[WAVES_PER_BLOCK][NBINS];
    const int wave = threadIdx.x >> 6;
    const int lane = threadIdx.x & 63;
    if (lane == 0) {
#pragma unroll
        for (int b = 0; b < NBINS; ++b) {
            sm_v[wave][b] = acc[b];
            sm_c[wave][b] = cnt[b];
        }
    }
    __syncthreads();
    if (threadIdx.x < NBINS) {
        const int b = threadIdx.x;
        float tv = 0.f, tc = 0.f;
#pragma unroll
        for (int w = 0; w < WAVES_PER_BLOCK; ++w) {
            tv += sm_v[w][b];
            tc += sm_c[w][b];
        }
        atomicAdd(&ws->sum_v[b], tv);
        atomicAdd(&ws->cnt[b], tc);
    }
}

__global__ void radial_loss_final(const WS* __restrict__ ws, float* __restrict__ out) {
    if (threadIdx.x == 0 && blockIdx.x == 0) {
        float loss = 0.f;
#pragma unroll
        for (int b = 0; b < NBINS; ++b) {
            float c = ws->cnt[b];
            if (c > 0.f) loss += ws->sum_v[b] / c;
        }
        out[0] = loss;
    }
}

extern "C" void kernel_launch(void* const* d_in, const int* in_sizes, int n_in,
                              void* d_out, int out_size, void* d_ws, size_t ws_size,
                              hipStream_t stream) {
    const float* x = (const float*)d_in[0];
    const float* y = (const float*)d_in[1];
    const float* dist = (const float*)d_in[2];
    float* out = (float*)d_out;
    WS* ws = (WS*)d_ws;
    const int n = in_sizes[2];  // dist element count = N

    hipMemsetAsync(ws, 0, sizeof(WS), stream);
    radial_loss_main<<<NBLOCKS, BLOCK, 0, stream>>>(x, y, dist, ws, n);
    radial_loss_final<<<1, 64, 0, stream>>>(ws, out);
}